// Round 1
// baseline (31.436 us; speedup 1.0000x reference)
//
#include <hip/hip_runtime.h>

#define LN 8192           // 8194 - 2
#define B_ROWS 4096
#define NMEANS 6

// ---------------------------------------------------------------------------
// Kernel 1: compute the single broadcast row into workspace.
// row[j] = sum_k w[k] * exp(-0.5*((j/LN - 0.2k)/0.2)^2) / (0.2*sqrt(2*pi))
// 8192 elements, 6 expf each -> trivial cost.
// ---------------------------------------------------------------------------
__global__ void __launch_bounds__(256)
row_kernel(const float* __restrict__ w, float* __restrict__ row) {
    int j = blockIdx.x * blockDim.x + threadIdx.x;
    if (j >= LN) return;
    const float inv_std = 5.0f;                       // 1/0.2
    const float norm    = 1.9947114020071633897f;     // 1/(0.2*sqrt(2*pi))
    float pos = (float)j * (1.0f / (float)LN);
    float acc = 0.0f;
#pragma unroll
    for (int k = 0; k < NMEANS; ++k) {
        float m = 0.2f * (float)k;
        float z = (pos - m) * inv_std;
        acc += w[k] * expf(-0.5f * z * z);
    }
    row[j] = acc * norm;
}

// ---------------------------------------------------------------------------
// Kernel 2: broadcast row to all 4096 output rows. Pure streaming stores,
// float4-vectorized (16 B/lane). Row (32 KB) stays resident in L1/L2.
// ---------------------------------------------------------------------------
__global__ void __launch_bounds__(256)
bcast_kernel(const float4* __restrict__ row4, float4* __restrict__ out4,
             long long n4) {
    long long i      = (long long)blockIdx.x * blockDim.x + threadIdx.x;
    long long stride = (long long)gridDim.x * blockDim.x;
    const int mask = LN / 4 - 1;                      // 2047
    for (; i < n4; i += stride) {
        out4[i] = row4[(int)i & mask];
    }
}

extern "C" void kernel_launch(void* const* d_in, const int* in_sizes, int n_in,
                              void* d_out, int out_size, void* d_ws, size_t ws_size,
                              hipStream_t stream) {
    const float* w = (const float*)d_in[0];   // weights [6]
    // d_in[1] (inp) is only used for its shape by the reference -> never read.
    float* out = (float*)d_out;
    float* row = (float*)d_ws;                // needs 8192*4 = 32 KB scratch

    row_kernel<<<dim3(LN / 256), dim3(256), 0, stream>>>(w, row);

    long long n4 = (long long)out_size / 4;   // 8,388,608 float4 stores
    bcast_kernel<<<dim3(2048), dim3(256), 0, stream>>>(
        (const float4*)row, (float4*)out, n4);
}

// Round 3
// 28.348 us; speedup vs baseline: 1.1090x; 1.1090x over previous
//
#include <hip/hip_runtime.h>

#define LN 8192           // 8194 - 2
#define B_ROWS 4096
#define NMEANS 6

#define COLS_PER_BLOCK 1024   // 256 threads * 4 floats
#define ROWS_PER_BLOCK 16
#define COL_SEGS (LN / COLS_PER_BLOCK)        // 8
#define ROW_CHUNKS (B_ROWS / ROWS_PER_BLOCK)  // 256

typedef float v4f __attribute__((ext_vector_type(4)));  // clang-native vector
                                                        // (accepted by
                                                        // __builtin_nontemporal_store)

// ---------------------------------------------------------------------------
// Fused kernel: each block owns a 16-row x 1024-col tile of the output.
// It computes its 1024-wide slice of the broadcast row once in registers
// (4 floats/thread, 6 Gaussians each -> negligible VALU), then streams the
// v4f to 16 rows with nontemporal stores (pure-write HBM stream).
// ---------------------------------------------------------------------------
__global__ void __launch_bounds__(256)
fused_kernel(const float* __restrict__ w, float* __restrict__ out) {
    const int bid     = blockIdx.x;
    const int colSeg  = bid & (COL_SEGS - 1);        // 0..7
    const int rowBase = (bid >> 3) * ROWS_PER_BLOCK; // 0..4080 step 16

    const int j0 = colSeg * COLS_PER_BLOCK + threadIdx.x * 4;

    // load the 6 weights (wave-uniform broadcast loads)
    float wk[NMEANS];
#pragma unroll
    for (int k = 0; k < NMEANS; ++k) wk[k] = w[k];

    const float inv_std = 5.0f;                   // 1/0.2
    const float norm    = 1.9947114020071633897f; // 1/(0.2*sqrt(2*pi))

    v4f v;
#pragma unroll
    for (int e = 0; e < 4; ++e) {
        float pos = (float)(j0 + e) * (1.0f / (float)LN);
        float acc = 0.0f;
#pragma unroll
        for (int k = 0; k < NMEANS; ++k) {
            float z = (pos - 0.2f * (float)k) * inv_std;
            acc += wk[k] * expf(-0.5f * z * z);
        }
        v[e] = acc * norm;
    }

    // stream the tile: 16 rows, fully-coalesced 1 KiB/wave nontemporal stores
    float* base = out + (long long)rowBase * LN + j0;
#pragma unroll
    for (int r = 0; r < ROWS_PER_BLOCK; ++r) {
        __builtin_nontemporal_store(v, (v4f*)(base + (long long)r * LN));
    }
}

extern "C" void kernel_launch(void* const* d_in, const int* in_sizes, int n_in,
                              void* d_out, int out_size, void* d_ws, size_t ws_size,
                              hipStream_t stream) {
    const float* w = (const float*)d_in[0];   // weights [6]
    // d_in[1] (inp) is shape-only in the reference -> never read.
    float* out = (float*)d_out;

    fused_kernel<<<dim3(COL_SEGS * ROW_CHUNKS), dim3(256), 0, stream>>>(w, out);
}

// Round 4
// 26.639 us; speedup vs baseline: 1.1801x; 1.0641x over previous
//
#include <hip/hip_runtime.h>

#define LN 8192           // 8194 - 2
#define B_ROWS 4096
#define NMEANS 6

#define COLS_PER_BLOCK 1024   // 256 threads * 4 floats
#define ROWS_PER_BLOCK 16
#define COL_SEGS (LN / COLS_PER_BLOCK)        // 8
#define ROW_CHUNKS (B_ROWS / ROWS_PER_BLOCK)  // 256

typedef float v4f __attribute__((ext_vector_type(4)));

// ---------------------------------------------------------------------------
// Fused kernel: each block owns a 16-row x 1024-col tile of the output.
// It computes its 1024-wide slice of the broadcast row once in registers,
// then streams the v4f to 16 rows with PLAIN stores — letting L2 / the
// 256 MiB Infinity Cache absorb the write stream instead of forcing an
// in-kernel HBM drain (which the nt flag did).
// ---------------------------------------------------------------------------
__global__ void __launch_bounds__(256)
fused_kernel(const float* __restrict__ w, float* __restrict__ out) {
    const int bid     = blockIdx.x;
    const int colSeg  = bid & (COL_SEGS - 1);        // 0..7
    const int rowBase = (bid >> 3) * ROWS_PER_BLOCK; // 0..4080 step 16

    const int j0 = colSeg * COLS_PER_BLOCK + threadIdx.x * 4;

    float wk[NMEANS];
#pragma unroll
    for (int k = 0; k < NMEANS; ++k) wk[k] = w[k];

    const float inv_std = 5.0f;                   // 1/0.2
    const float norm    = 1.9947114020071633897f; // 1/(0.2*sqrt(2*pi))

    v4f v;
#pragma unroll
    for (int e = 0; e < 4; ++e) {
        float pos = (float)(j0 + e) * (1.0f / (float)LN);
        float acc = 0.0f;
#pragma unroll
        for (int k = 0; k < NMEANS; ++k) {
            float z = (pos - 0.2f * (float)k) * inv_std;
            acc += wk[k] * expf(-0.5f * z * z);
        }
        v[e] = acc * norm;
    }

    // stream the tile: 16 rows, fully-coalesced 1 KiB/wave plain stores
    float* base = out + (long long)rowBase * LN + j0;
#pragma unroll
    for (int r = 0; r < ROWS_PER_BLOCK; ++r) {
        *(v4f*)(base + (long long)r * LN) = v;
    }
}

extern "C" void kernel_launch(void* const* d_in, const int* in_sizes, int n_in,
                              void* d_out, int out_size, void* d_ws, size_t ws_size,
                              hipStream_t stream) {
    const float* w = (const float*)d_in[0];   // weights [6]
    // d_in[1] (inp) is shape-only in the reference -> never read.
    float* out = (float*)d_out;

    fused_kernel<<<dim3(COL_SEGS * ROW_CHUNKS), dim3(256), 0, stream>>>(w, out);
}

// Round 5
// 25.837 us; speedup vs baseline: 1.2167x; 1.0310x over previous
//
#include <hip/hip_runtime.h>

#define LN 8192           // 8194 - 2
#define B_ROWS 4096
#define NMEANS 6

#define COLS_PER_BLOCK 1024   // 256 threads * 4 floats
#define ROWS_PER_BLOCK 16
#define COL_SEGS (LN / COLS_PER_BLOCK)        // 8
#define ROW_CHUNKS (B_ROWS / ROWS_PER_BLOCK)  // 256

typedef float v4f __attribute__((ext_vector_type(4)));

// ---------------------------------------------------------------------------
// Fused kernel: each block owns a 16-row x 1024-col tile of the output.
// Computes its 1024-wide slice of the broadcast row once in registers using
// the NATIVE exp path (__expf -> v_exp_f32, ~1 instr vs ~30 for libm expf;
// tolerance is 4e-2 so precision is ample), then streams plain float4 stores.
// ---------------------------------------------------------------------------
__global__ void __launch_bounds__(256)
fused_kernel(const float* __restrict__ w, float* __restrict__ out) {
    const int bid     = blockIdx.x;
    const int colSeg  = bid & (COL_SEGS - 1);        // 0..7
    const int rowBase = (bid >> 3) * ROWS_PER_BLOCK; // 0..4080 step 16

    const int j0 = colSeg * COLS_PER_BLOCK + threadIdx.x * 4;

    float wk[NMEANS];
#pragma unroll
    for (int k = 0; k < NMEANS; ++k) wk[k] = w[k];

    const float inv_std = 5.0f;                   // 1/0.2
    const float norm    = 1.9947114020071633897f; // 1/(0.2*sqrt(2*pi))

    v4f v;
#pragma unroll
    for (int e = 0; e < 4; ++e) {
        float pos = (float)(j0 + e) * (1.0f / (float)LN);
        float acc = 0.0f;
#pragma unroll
        for (int k = 0; k < NMEANS; ++k) {
            float z = (pos - 0.2f * (float)k) * inv_std;
            acc += wk[k] * __expf(-0.5f * z * z);   // native v_exp_f32 path
        }
        v[e] = acc * norm;
    }

    // stream the tile: 16 rows, fully-coalesced 1 KiB/wave plain stores
    float* base = out + (long long)rowBase * LN + j0;
#pragma unroll
    for (int r = 0; r < ROWS_PER_BLOCK; ++r) {
        *(v4f*)(base + (long long)r * LN) = v;
    }
}

extern "C" void kernel_launch(void* const* d_in, const int* in_sizes, int n_in,
                              void* d_out, int out_size, void* d_ws, size_t ws_size,
                              hipStream_t stream) {
    const float* w = (const float*)d_in[0];   // weights [6]
    // d_in[1] (inp) is shape-only in the reference -> never read.
    float* out = (float*)d_out;

    fused_kernel<<<dim3(COL_SEGS * ROW_CHUNKS), dim3(256), 0, stream>>>(w, out);
}